// Round 12
// baseline (529.000 us; speedup 1.0000x reference)
//
#include <hip/hip_runtime.h>
#include <hip/hip_bf16.h>

#define BB 128
#define LL 200
#define DD 512
#define HH 8
#define DK 64
#define NBLK 2
#define BL (BB*LL)
#define SCAP 64   // staged-key capacity per (b,h); overflow reads global (general)

typedef unsigned short ushort_t;
typedef unsigned int uint_t;
typedef __attribute__((ext_vector_type(8))) short short8;
typedef __attribute__((ext_vector_type(4))) short short4v;
typedef __attribute__((ext_vector_type(4))) float f32x4;

__device__ inline ushort_t f2b(float x) {
    unsigned u = __float_as_uint(x);
    unsigned r = (u + 0x7FFF + ((u >> 16) & 1)) >> 16;
    return (ushort_t)r;
}

__device__ inline float b2f(ushort_t u) {
    return __uint_as_float((uint_t)u << 16);
}

__device__ inline void gload16(const void* g, void* l) {
    __builtin_amdgcn_global_load_lds((const __attribute__((address_space(1))) void*)g,
                                     (__attribute__((address_space(3))) void*)l,
                                     16, 0, 0);
}

// ---------- masks + per-batch ordered compaction of valid keys (kmf==1) -------
__global__ __launch_bounds__(256) void maskidx_kernel(const int* __restrict__ logs,
                                                      const int* __restrict__ entire,
                                                      float* __restrict__ keepf,
                                                      float* __restrict__ kmf,
                                                      int* __restrict__ kidx,
                                                      int* __restrict__ cntb) {
    int b = blockIdx.x;
    int t = threadIdx.x;
    bool valid = false;
    if (t < LL) {
        int i = b * LL + t;
        bool src = (logs[i] == 0);
        keepf[i] = src ? 0.f : 1.f;
        bool v = src && (entire[i] != 0);
        kmf[i] = v ? 1.f : 0.f;
        valid = v;
    }
    unsigned long long mask = __ballot(valid);
    int wid = t >> 6, lane = t & 63;
    __shared__ int wcnt[4];
    if (lane == 0) wcnt[wid] = __popcll(mask);
    __syncthreads();
    int base = 0;
    for (int k2 = 0; k2 < wid; k2++) base += wcnt[k2];
    int pos = base + __popcll(mask & ((1ull << lane) - 1ull));
    if (valid) kidx[b * LL + pos] = t;
    if (t == 0) cntb[b] = wcnt[0] + wcnt[1] + wcnt[2] + wcnt[3];
}

// ---------- scan: per-batch offsets, global gather list, padded tile count ----
__global__ __launch_bounds__(128) void scan_kernel(const int* __restrict__ cntb,
                                                   const int* __restrict__ kidx,
                                                   int* __restrict__ off,
                                                   int* __restrict__ rows,
                                                   int* __restrict__ nbk) {
    __shared__ int soff[BB + 1];
    int t = threadIdx.x;
    if (t == 0) {
        int acc = 0;
        for (int b = 0; b < BB; b++) { soff[b] = acc; acc += cntb[b]; }
        soff[BB] = acc;
        nbk[0] = (acc + 127) >> 7;
    }
    __syncthreads();
    int ob = soff[t], nc = cntb[t];
    off[t] = ob;
    for (int s = 0; s < nc; s++)
        rows[ob + s] = t * LL + kidx[t * LL + s];
    __syncthreads();
    if (t == 0) {
        int S = soff[BB];
        int Spad = ((S + 127) >> 7) << 7;
        int last = (S > 0) ? rows[S - 1] : 0;
        for (int s = S; s < Spad; s++) rows[s] = last;
    }
}

// prep v2: 4 rows/block, 16B/lane f32x4 loads. tgt = emb*keep ; srcb = bf16(emb*tl)
__global__ __launch_bounds__(256) void prep_kernel(const int* __restrict__ logs,
                                                   const float* __restrict__ emb,
                                                   float* __restrict__ tgt,
                                                   ushort_t* __restrict__ srcb) {
    int wid = threadIdx.x >> 6, lane = threadIdx.x & 63;
    int row = blockIdx.x * 4 + wid;          // BL % 4 == 0
    bool src = (logs[row] == 0);
    float kf = src ? 0.f : 1.f, sf = src ? 1.f : 0.f;
    size_t base = (size_t)row * DD;
    int c0 = lane * 4, c1 = c0 + 256;
    f32x4 e0 = *(const f32x4*)(emb + base + c0);
    f32x4 e1 = *(const f32x4*)(emb + base + c1);
    f32x4 t0, t1;
    short4v s0, s1;
    #pragma unroll
    for (int j = 0; j < 4; j++) {
        t0[j] = e0[j] * kf;
        t1[j] = e1[j] * kf;
        s0[j] = (short)f2b(e0[j] * sf);
        s1[j] = (short)f2b(e1[j] * sf);
    }
    *(f32x4*)(tgt + base + c0) = t0;
    *(f32x4*)(tgt + base + c1) = t1;
    *(short4v*)(srcb + base + c0) = s0;
    *(short4v*)(srcb + base + c1) = s1;
}

// fused weight transpose + bf16 for all 10 matrices: grid (16,16,10)
__global__ __launch_bounds__(256) void wtrans10_kernel(const float* __restrict__ Wq,
                                                       const float* __restrict__ Wk,
                                                       const float* __restrict__ Wv,
                                                       const float* __restrict__ W1,
                                                       const float* __restrict__ W2,
                                                       ushort_t* __restrict__ WqkvT,
                                                       ushort_t* __restrict__ W1T,
                                                       ushort_t* __restrict__ W2T) {
    __shared__ float ts[32][33];
    int tx = threadIdx.x & 31, ty = threadIdx.x >> 5;
    int bx = blockIdx.x * 32, by = blockIdx.y * 32;
    int z = blockIdx.z;
    const float* Wm;
    ushort_t* Wtm;
    if (z < 6) {
        int i = z / 3, j = z - 3 * i;
        const float* src = (j == 0) ? Wq : (j == 1) ? Wk : Wv;
        Wm = src + (size_t)i * DD * DD;
        Wtm = WqkvT + (size_t)z * DD * DD;
    } else if (z < 8) {
        Wm = W1 + (size_t)(z - 6) * DD * DD;
        Wtm = W1T + (size_t)(z - 6) * DD * DD;
    } else {
        Wm = W2 + (size_t)(z - 8) * DD * DD;
        Wtm = W2T + (size_t)(z - 8) * DD * DD;
    }
    #pragma unroll
    for (int i = 0; i < 4; i++) {
        int r = ty + i * 8;
        ts[r][tx] = Wm[(size_t)(by + r) * DD + bx + tx];
    }
    __syncthreads();
    #pragma unroll
    for (int i = 0; i < 4; i++) {
        int r = ty + i * 8;
        Wtm[(size_t)(bx + r) * DD + by + tx] = f2b(ts[tx][r]);
    }
}

// ------- layernorm v3: one wave per row, 4 rows/block, no LDS, no barrier ------
__global__ __launch_bounds__(256) void ln_kernel(const float* __restrict__ x,
                                                 const float* __restrict__ addx,
                                                 float* __restrict__ outf,
                                                 ushort_t* __restrict__ outb,
                                                 const float* __restrict__ g,
                                                 const float* __restrict__ bt,
                                                 const float* __restrict__ keepf) {
    int wid = threadIdx.x >> 6, lane = threadIdx.x & 63;
    int row = blockIdx.x * 4 + wid;          // BL % 4 == 0 -> always in range
    size_t base = (size_t)row * DD;
    int c0 = lane * 4, c1 = c0 + 256;
    f32x4 v0 = *(const f32x4*)(x + base + c0);
    f32x4 v1 = *(const f32x4*)(x + base + c1);
    if (addx) {
        f32x4 a0 = *(const f32x4*)(addx + base + c0);
        f32x4 a1 = *(const f32x4*)(addx + base + c1);
        v0 = v0 + a0;
        v1 = v1 + a1;
    }
    float s = v0[0] + v0[1] + v0[2] + v0[3] + v1[0] + v1[1] + v1[2] + v1[3];
    float sq = v0[0] * v0[0] + v0[1] * v0[1] + v0[2] * v0[2] + v0[3] * v0[3]
             + v1[0] * v1[0] + v1[1] * v1[1] + v1[2] * v1[2] + v1[3] * v1[3];
    #pragma unroll
    for (int off = 32; off; off >>= 1) {
        s += __shfl_xor(s, off);
        sq += __shfl_xor(sq, off);
    }
    float mean = s * (1.f / DD);
    float var = sq * (1.f / DD) - mean * mean;
    float rstd = rsqrtf(fmaxf(var, 0.f) + 1e-8f);
    float kf = keepf ? keepf[row] : 1.f;
    f32x4 g0 = *(const f32x4*)(g + c0), g1 = *(const f32x4*)(g + c1);
    f32x4 b0 = *(const f32x4*)(bt + c0), b1 = *(const f32x4*)(bt + c1);
    f32x4 o0, o1;
    #pragma unroll
    for (int j = 0; j < 4; j++) {
        o0[j] = ((v0[j] - mean) * rstd * g0[j] + b0[j]) * kf;
        o1[j] = ((v1[j] - mean) * rstd * g1[j] + b1[j]) * kf;
    }
    if (outf) {
        *(f32x4*)(outf + base + c0) = o0;
        *(f32x4*)(outf + base + c1) = o1;
    }
    if (outb) {
        short4v ob0, ob1;
        #pragma unroll
        for (int j = 0; j < 4; j++) { ob0[j] = (short)f2b(o0[j]); ob1[j] = (short)f2b(o1[j]); }
        *(short4v*)(outb + base + c0) = ob0;
        *(short4v*)(outb + base + c1) = ob1;
    }
}

// ------- bf16 MFMA GEMM, 64x128 tile, panel-major + XCD swizzle ----------------
// Round-12: software-pipelined K-loop at HALF-K-STEP granularity (T3 minimum
// 2-phase, issue-early/drain-late). The two hh half-buffers become a double
// buffer: STAGE(half s+1) is issued BEFORE compute(half s); the end-of-iter
// barrier's vmcnt(0) drain then lands AFTER ~350cy of ds_read+MFMA instead of
// before any compute. Zero extra LDS; 1 barrier per half-step (was 2 per step).
// mode 0: Cb = bf16(acc+bias) ; 1: Cb = bf16(relu) ; 2: Cf = (Cf+acc+bias)*keepf.
// In mode 0, blocks >= ngg run the compact K/V projection (round 11).
__global__ __launch_bounds__(256) void gemm_mfma(const ushort_t* __restrict__ A,
                                                 const ushort_t* __restrict__ Bt,
                                                 const float* __restrict__ bias,
                                                 float* __restrict__ Cf,
                                                 ushort_t* __restrict__ Cb,
                                                 const float* __restrict__ keepf,
                                                 int mode, int M, int N, int K, int ngg,
                                                 const ushort_t* __restrict__ Akv,
                                                 const ushort_t* __restrict__ Bkv,
                                                 const float* __restrict__ bk,
                                                 const float* __restrict__ bv,
                                                 const int* __restrict__ rows,
                                                 const int* __restrict__ nbk,
                                                 ushort_t* __restrict__ kc,
                                                 ushort_t* __restrict__ vc) {
    __shared__ ushort_t smem[12288];       // 24 KB: K-loop sA(8K)+sB(16K); epilogue C-stage
    ushort_t* sAm = smem;                  // [2][64*32]   (double buffer)
    ushort_t* sBm = smem + 4096;           // [2][128*32]  (double buffer)
    int t = threadIdx.x;
    int w = t >> 6, lane = t & 63;
    int lr = lane & 15, lq = lane >> 4;
    int eA = t * 8, rowA = eA >> 5, colA = eA & 31;
    int eB0 = t * 8, rowB0 = eB0 >> 5, colB0 = eB0 & 31;
    int eB1 = (256 + t) * 8, rowB1 = eB1 >> 5, colB1 = eB1 & 31;

    if ((int)blockIdx.x < ngg) {
        // ---------------- main dense path ----------------
        int cpx = ngg >> 3;
        int swz = (blockIdx.x & 7) * cpx + (blockIdx.x >> 3);
        int m0 = (swz >> 2) * 64;        // N/128 == 4 panels-per-row here (N=512)
        int n0 = (swz & 3) * 128;

        f32x4 acc[4][2] = {};
        int nhalf = K >> 5;              // 16 half-steps of 32 K-elems

        // STAGE(half s) -> buffer s&1
        // prologue
        {
            gload16(A + (size_t)(m0 + rowA) * K + 0 + colA, sAm + (w * 64) * 8);
            gload16(Bt + (size_t)(n0 + rowB0) * K + 0 + colB0, sBm + (w * 64) * 8);
            gload16(Bt + (size_t)(n0 + rowB1) * K + 0 + colB1, sBm + (256 + w * 64) * 8);
        }
        __syncthreads();                 // vmcnt(0): half 0 resident

        for (int s = 0; s < nhalf; s++) {
            if (s + 1 < nhalf) {         // issue next half into the other buffer
                int kk = (s + 1) * 32;
                int bs = (s + 1) & 1;
                gload16(A + (size_t)(m0 + rowA) * K + kk + colA,
                        sAm + bs * 2048 + (w * 64) * 8);
                gload16(Bt + (size_t)(n0 + rowB0) * K + kk + colB0,
                        sBm + bs * 4096 + (w * 64) * 8);
                gload16(Bt + (size_t)(n0 + rowB1) * K + kk + colB1,
                        sBm + bs * 4096 + (256 + w * 64) * 8);
            }
            int bc = s & 1;
            short8 af[4], bf[2];
            #pragma unroll
            for (int mt = 0; mt < 4; mt++)
                af[mt] = *(const short8*)(sAm + bc * 2048 + (mt * 16 + lr) * 32 + lq * 8);
            #pragma unroll
            for (int nt = 0; nt < 2; nt++)
                bf[nt] = *(const short8*)(sBm + bc * 4096 + (w * 32 + nt * 16 + lr) * 32 + lq * 8);
            #pragma unroll
            for (int mt = 0; mt < 4; mt++)
                #pragma unroll
                for (int nt = 0; nt < 2; nt++)
                    acc[mt][nt] = __builtin_amdgcn_mfma_f32_16x16x32_bf16(af[mt], bf[nt], acc[mt][nt], 0, 0, 0);
            __syncthreads();             // drains prefetch (flew under MFMA) + orders buffer reuse
        }

        if (mode != 2) {
            #pragma unroll
            for (int nt = 0; nt < 2; nt++) {
                int colL = w * 32 + nt * 16 + lr;
                float bvv = bias[n0 + colL];
                #pragma unroll
                for (int mt = 0; mt < 4; mt++) {
                    int rowL = mt * 16 + lq * 4;
                    #pragma unroll
                    for (int r = 0; r < 4; r++) {
                        float o = acc[mt][nt][r] + bvv;
                        if (mode == 1) o = fmaxf(o, 0.f);
                        smem[(rowL + r) * 136 + colL] = f2b(o);
                    }
                }
            }
            __syncthreads();
            int rr = t >> 2, cc = (t & 3) * 32;
            #pragma unroll
            for (int j = 0; j < 4; j++) {
                short8 vv = *(const short8*)(smem + rr * 136 + cc + j * 8);
                *(short8*)(Cb + (size_t)(m0 + rr) * N + n0 + cc + j * 8) = vv;
            }
        } else {
            float* sf = (float*)smem;
            #pragma unroll
            for (int half = 0; half < 2; half++) {
                #pragma unroll
                for (int nt = 0; nt < 2; nt++) {
                    int colL = w * 32 + nt * 16 + lr;
                    float bvv = bias[n0 + colL];
                    #pragma unroll
                    for (int mt = half * 2; mt < half * 2 + 2; mt++) {
                        int rowL = mt * 16 + lq * 4 - half * 32;
                        #pragma unroll
                        for (int r = 0; r < 4; r++)
                            sf[(rowL + r) * 132 + colL] = acc[mt][nt][r] + bvv;
                    }
                }
                __syncthreads();
                int rr = t >> 3, cc = (t & 7) * 16;
                int grow = m0 + half * 32 + rr;
                float kf = keepf[grow];
                #pragma unroll
                for (int j = 0; j < 4; j++) {
                    f32x4 oldv = *(const f32x4*)(Cf + (size_t)grow * N + n0 + cc + j * 4);
                    f32x4 nv;
                    #pragma unroll
                    for (int x = 0; x < 4; x++)
                        nv[x] = (oldv[x] + sf[rr * 132 + cc + j * 4 + x]) * kf;
                    *(f32x4*)(Cf + (size_t)grow * N + n0 + cc + j * 4) = nv;
                }
                __syncthreads();
            }
        }
    } else {
        // ---------------- compact K/V path (mode 0 extra blocks) ----------------
        // eb in [0,64): z = eb>>5 (0=K,1=V), n-col = (eb>>3)&3, m-tile = eb&7
        int eb = blockIdx.x - ngg;
        int z = eb >> 5;
        int n0 = ((eb >> 3) & 3) * 128;
        int mt0 = eb & 7;
        const ushort_t* Btk = Bkv + (size_t)z * DD * DD;
        const float* biask = z ? bv : bk;
        ushort_t* C = z ? vc : kc;
        int rowlim = nbk[0] * 128;           // rows[] valid/padded up to here

        for (int mt = mt0; mt * 64 < rowlim; mt += 8) {
            int m0c = mt * 64;
            int ra = rows[m0c + rowA];       // gathered source row (K-invariant)

            f32x4 acc[4][2] = {};

            for (int k0 = 0; k0 < DD; k0 += 64) {
                #pragma unroll
                for (int hh = 0; hh < 2; hh++) {
                    gload16(Akv + (size_t)ra * DD + k0 + hh * 32 + colA,
                            sAm + hh * 2048 + (w * 64) * 8);
                    gload16(Btk + (size_t)(n0 + rowB0) * DD + k0 + hh * 32 + colB0,
                            sBm + hh * 4096 + (w * 64) * 8);
                    gload16(Btk + (size_t)(n0 + rowB1) * DD + k0 + hh * 32 + colB1,
                            sBm + hh * 4096 + (256 + w * 64) * 8);
                }
                __syncthreads();

                #pragma unroll
                for (int hh = 0; hh < 2; hh++) {
                    short8 af[4], bf[2];
                    #pragma unroll
                    for (int mt2 = 0; mt2 < 4; mt2++)
                        af[mt2] = *(const short8*)(sAm + hh * 2048 + (mt2 * 16 + lr) * 32 + lq * 8);
                    #pragma unroll
                    for (int nt = 0; nt < 2; nt++)
                        bf[nt] = *(const short8*)(sBm + hh * 4096 + (w * 32 + nt * 16 + lr) * 32 + lq * 8);
                    #pragma unroll
                    for (int mt2 = 0; mt2 < 4; mt2++)
                        #pragma unroll
                        for (int nt = 0; nt < 2; nt++)
                            acc[mt2][nt] = __builtin_amdgcn_mfma_f32_16x16x32_bf16(af[mt2], bf[nt], acc[mt2][nt], 0, 0, 0);
                }
                __syncthreads();
            }

            #pragma unroll
            for (int nt = 0; nt < 2; nt++) {
                int colL = w * 32 + nt * 16 + lr;
                float bvv = biask[n0 + colL];
                #pragma unroll
                for (int mt2 = 0; mt2 < 4; mt2++) {
                    int rowL = mt2 * 16 + lq * 4;
                    #pragma unroll
                    for (int r = 0; r < 4; r++)
                        smem[(rowL + r) * 136 + colL] = f2b(acc[mt2][nt][r] + bvv);
                }
            }
            __syncthreads();
            int rr = t >> 2, cc = (t & 3) * 32;
            #pragma unroll
            for (int j = 0; j < 4; j++) {
                short8 vv = *(const short8*)(smem + rr * 136 + cc + j * 8);
                *(short8*)(C + (size_t)(m0c + rr) * DD + n0 + cc + j * 8) = vv;
            }
            __syncthreads();   // smem reused by next m-tile's staging
        }
    }
}

// ---------------- sparse attention v4: 8 lanes/query, LDS keys, e=0 masking ----
__global__ __launch_bounds__(256) void attn_sparse(const ushort_t* __restrict__ q,
                                                   const ushort_t* __restrict__ kc,
                                                   const ushort_t* __restrict__ vc,
                                                   const int* __restrict__ kidx,
                                                   const int* __restrict__ cntb,
                                                   const int* __restrict__ off,
                                                   float* __restrict__ xout) {
    __shared__ ushort_t sK[SCAP * DK];   // 8 KB
    __shared__ ushort_t sV[SCAP * DK];   // 8 KB
    __shared__ int sIdx[LL];             // 800 B
    int b = blockIdx.x >> 3, h = blockIdx.x & 7;
    int t = threadIdx.x;
    int w = t >> 6, lane = t & 63;
    int qi = lane >> 3;                  // query slot 0..7 within wave
    int dc = (lane & 7) * 8;             // head-dim chunk base (8 dims/lane)
    int nc = cntb[b], ob = off[b];
    const ushort_t* qg = q + (size_t)b * LL * DD + h * DK;
    float* og = xout + (size_t)b * LL * DD + h * DK;
    const ushort_t* kb2 = kc + (size_t)ob * DD + h * DK;
    const ushort_t* vb2 = vc + (size_t)ob * DD + h * DK;

    if (t < nc) sIdx[t] = kidx[b * LL + t];          // nc <= 200 < 256
    int ns = (nc < SCAP) ? nc : SCAP;
    for (int idx = t; idx < ns * 8; idx += 256) {    // 8x 16B chunks per 128B row
        int s = idx >> 3, c = (idx & 7) * 8;
        *(uint4*)(sK + s * DK + c) = *(const uint4*)(kb2 + (size_t)s * DD + c);
        *(uint4*)(sV + s * DK + c) = *(const uint4*)(vb2 + (size_t)s * DD + c);
    }
    __syncthreads();

    // 32 queries per block-iteration (4 waves x 8); 7 iterations cover 224 >= LL
    for (int i0 = 0; i0 < LL; i0 += 32) {
        int i = i0 + w * 8 + qi;
        bool qok = (i < LL);
        int ic = qok ? i : (LL - 1);
        short8 qv = *(const short8*)(qg + (size_t)ic * DD + dc);
        float qf[8];
        #pragma unroll
        for (int j = 0; j < 8; j++) qf[j] = b2f((ushort_t)qv[j]);

        float m = -3.0e38f, l = 0.f;
        float acc[8];
        #pragma unroll
        for (int j = 0; j < 8; j++) acc[j] = 0.f;

        for (int s = 0; s < nc; s++) {
            const ushort_t* kp = (s < SCAP) ? (sK + s * DK + dc)
                                            : (kb2 + (size_t)s * DD + dc);
            const ushort_t* vp = (s < SCAP) ? (sV + s * DK + dc)
                                            : (vb2 + (size_t)s * DD + dc);
            short8 k8 = *(const short8*)kp;
            float pp = 0.f;
            #pragma unroll
            for (int j = 0; j < 8; j++) pp += qf[j] * b2f((ushort_t)k8[j]);
            pp += __shfl_xor(pp, 1);
            pp += __shfl_xor(pp, 2);
            pp += __shfl_xor(pp, 4);
            bool ok = (sIdx[s] <= i);                // per-query causal predicate
            float sc = ok ? pp * 0.125f : -3.0e38f;
            float mn = fmaxf(m, sc);
            float e = ok ? __expf(sc - mn) : 0.f;    // masked key contributes 0
            float rs2 = __expf(m - mn);              // m==mn for masked -> rs2=1
            l = l * rs2 + e;
            short8 v8 = *(const short8*)vp;
            #pragma unroll
            for (int j = 0; j < 8; j++)
                acc[j] = acc[j] * rs2 + e * b2f((ushort_t)v8[j]);
            m = mn;
        }

        if (qok) {
            float inv = (l > 0.f) ? 1.f / l : 0.f;
            f32x4 o0, o1;
            #pragma unroll
            for (int j = 0; j < 4; j++) { o0[j] = acc[j] * inv; o1[j] = acc[j + 4] * inv; }
            *(f32x4*)(og + (size_t)i * DD + dc) = o0;
            *(f32x4*)(og + (size_t)i * DD + dc + 4) = o1;
        }
    }
}

extern "C" void kernel_launch(void* const* d_in, const int* in_sizes, int n_in,
                              void* d_out, int out_size, void* d_ws, size_t ws_size,
                              hipStream_t stream) {
    const int* log_seqs = (const int*)d_in[0];
    const float* seqs_embs = (const float*)d_in[1];
    const int* entire = (const int*)d_in[2];
    const float* Wq = (const float*)d_in[3];
    const float* bq = (const float*)d_in[4];
    const float* Wk = (const float*)d_in[5];
    const float* bk = (const float*)d_in[6];
    const float* Wv = (const float*)d_in[7];
    const float* bv = (const float*)d_in[8];
    const float* lag = (const float*)d_in[9];
    const float* lab = (const float*)d_in[10];
    const float* lfg = (const float*)d_in[11];
    const float* lfb = (const float*)d_in[12];
    const float* W1 = (const float*)d_in[13];
    const float* b1 = (const float*)d_in[14];
    const float* W2 = (const float*)d_in[15];
    const float* b2 = (const float*)d_in[16];
    const float* llg = (const float*)d_in[17];
    const float* llb = (const float*)d_in[18];
    float* out = (float*)d_out;
    float* ws = (float*)d_ws;

    // workspace ~241 MB (262.45 MB proven safe)
    const size_t n = (size_t)BL * DD;
    float* tgt = ws;
    float* aout = ws + n;
    ushort_t* srcb = (ushort_t*)(ws + 2 * n);
    ushort_t* qb = srcb + n;
    ushort_t* kc = qb + n;           // compact K rows [<=BL][DD]
    ushort_t* lnb = kc + n;
    ushort_t* WqkvT = lnb + n;
    ushort_t* W1T = WqkvT + (size_t)NBLK * 3 * DD * DD;
    ushort_t* W2T = W1T + (size_t)NBLK * DD * DD;
    float* keepf = (float*)(W2T + (size_t)NBLK * DD * DD);
    float* kmf = keepf + BL;
    ushort_t* vc = (ushort_t*)(kmf + BL);   // compact V rows [<=BL][DD]
    int* kidx = (int*)(vc + n);      // [BB][LL] per-batch valid key indices
    int* cntb = kidx + BL;           // [BB]
    int* offb = cntb + BB;           // [BB]
    int* rows = offb + BB;           // [BL+128] global gathered row list (padded)
    int* nbk = rows + BL + 128;      // [1] number of 128-row tiles
    ushort_t* hb = qb;               // FFN1 out: qb dead after attention

    maskidx_kernel<<<BB, 256, 0, stream>>>(log_seqs, entire, keepf, kmf, kidx, cntb);
    scan_kernel<<<1, 128, 0, stream>>>(cntb, kidx, offb, rows, nbk);
    prep_kernel<<<BL / 4, 256, 0, stream>>>(log_seqs, seqs_embs, tgt, srcb);
    dim3 tw(16, 16, 10);
    wtrans10_kernel<<<tw, 256, 0, stream>>>(Wq, Wk, Wv, W1, W2, WqkvT, W1T, W2T);

    int ngg = (BL / 64) * (DD / 128);   // 1600 blocks, 1-D panel-major + XCD swizzle
    int nln = BL / 4;                   // LN: 4 rows per 256-thread block
    for (int i = 0; i < NBLK; i++) {
        size_t wo = (size_t)i * DD * DD;
        const ushort_t* Wi = WqkvT + (size_t)i * 3 * DD * DD;
        // lnb = bf16(LN(tgt, ln_attn))
        ln_kernel<<<nln, 256, 0, stream>>>(tgt, nullptr, nullptr, lnb,
                                           lag + i * DD, lab + i * DD, nullptr);
        // merged: qb = bf16(lnb @ Wq + bq)  +  compact kc/vc projections (64 extra blocks)
        gemm_mfma<<<ngg + 64, 256, 0, stream>>>(lnb, Wi, bq + i * DD, nullptr, qb,
                                                nullptr, 0, BL, DD, DD, ngg,
                                                srcb, Wi + (size_t)DD * DD,
                                                bk + i * DD, bv + i * DD,
                                                rows, nbk, kc, vc);
        // attention over compacted keys -> aout fp32
        attn_sparse<<<BB * HH, 256, 0, stream>>>(qb, kc, vc, kidx, cntb, offb, aout);
        // tgt = LN(aout (+tgt)), bf16 copy to lnb
        ln_kernel<<<nln, 256, 0, stream>>>(aout, (i == 0) ? nullptr : tgt, tgt, lnb,
                                           lfg + i * DD, lfb + i * DD, nullptr);
        // hb = bf16(relu(lnb @ W1 + b1))
        gemm_mfma<<<ngg, 256, 0, stream>>>(lnb, W1T + wo, b1 + i * DD, nullptr, hb,
                                           nullptr, 1, BL, DD, DD, ngg,
                                           nullptr, nullptr, nullptr, nullptr,
                                           nullptr, nullptr, nullptr, nullptr);
        // tgt = (tgt + hb @ W2 + b2) * keep
        gemm_mfma<<<ngg, 256, 0, stream>>>(hb, W2T + wo, b2 + i * DD, tgt, nullptr,
                                           keepf, 2, BL, DD, DD, ngg,
                                           nullptr, nullptr, nullptr, nullptr,
                                           nullptr, nullptr, nullptr, nullptr);
    }
    ln_kernel<<<nln, 256, 0, stream>>>(tgt, nullptr, out, nullptr, llg, llb, keepf);
}

// Round 13
// 502.375 us; speedup vs baseline: 1.0530x; 1.0530x over previous
//
#include <hip/hip_runtime.h>
#include <hip/hip_bf16.h>

#define BB 128
#define LL 200
#define DD 512
#define HH 8
#define DK 64
#define NBLK 2
#define BL (BB*LL)
#define SCAP 64   // staged-key capacity per (b,h); overflow reads global (general)

typedef unsigned short ushort_t;
typedef unsigned int uint_t;
typedef __attribute__((ext_vector_type(8))) short short8;
typedef __attribute__((ext_vector_type(4))) short short4v;
typedef __attribute__((ext_vector_type(4))) float f32x4;

__device__ inline ushort_t f2b(float x) {
    unsigned u = __float_as_uint(x);
    unsigned r = (u + 0x7FFF + ((u >> 16) & 1)) >> 16;
    return (ushort_t)r;
}

__device__ inline float b2f(ushort_t u) {
    return __uint_as_float((uint_t)u << 16);
}

__device__ inline void gload16(const void* g, void* l) {
    __builtin_amdgcn_global_load_lds((const __attribute__((address_space(1))) void*)g,
                                     (__attribute__((address_space(3))) void*)l,
                                     16, 0, 0);
}

// ---------- masks + per-batch ordered compaction of valid keys (kmf==1) -------
__global__ __launch_bounds__(256) void maskidx_kernel(const int* __restrict__ logs,
                                                      const int* __restrict__ entire,
                                                      float* __restrict__ keepf,
                                                      float* __restrict__ kmf,
                                                      int* __restrict__ kidx,
                                                      int* __restrict__ cntb) {
    int b = blockIdx.x;
    int t = threadIdx.x;
    bool valid = false;
    if (t < LL) {
        int i = b * LL + t;
        bool src = (logs[i] == 0);
        keepf[i] = src ? 0.f : 1.f;
        bool v = src && (entire[i] != 0);
        kmf[i] = v ? 1.f : 0.f;
        valid = v;
    }
    unsigned long long mask = __ballot(valid);
    int wid = t >> 6, lane = t & 63;
    __shared__ int wcnt[4];
    if (lane == 0) wcnt[wid] = __popcll(mask);
    __syncthreads();
    int base = 0;
    for (int k2 = 0; k2 < wid; k2++) base += wcnt[k2];
    int pos = base + __popcll(mask & ((1ull << lane) - 1ull));
    if (valid) kidx[b * LL + pos] = t;
    if (t == 0) cntb[b] = wcnt[0] + wcnt[1] + wcnt[2] + wcnt[3];
}

// ---------- scan: per-batch offsets, global gather list, padded tile count ----
__global__ __launch_bounds__(128) void scan_kernel(const int* __restrict__ cntb,
                                                   const int* __restrict__ kidx,
                                                   int* __restrict__ off,
                                                   int* __restrict__ rows,
                                                   int* __restrict__ nbk) {
    __shared__ int soff[BB + 1];
    int t = threadIdx.x;
    if (t == 0) {
        int acc = 0;
        for (int b = 0; b < BB; b++) { soff[b] = acc; acc += cntb[b]; }
        soff[BB] = acc;
        nbk[0] = (acc + 127) >> 7;
    }
    __syncthreads();
    int ob = soff[t], nc = cntb[t];
    off[t] = ob;
    for (int s = 0; s < nc; s++)
        rows[ob + s] = t * LL + kidx[t * LL + s];
    __syncthreads();
    if (t == 0) {
        int S = soff[BB];
        int Spad = ((S + 127) >> 7) << 7;
        int last = (S > 0) ? rows[S - 1] : 0;
        for (int s = S; s < Spad; s++) rows[s] = last;
    }
}

// prep v2: 4 rows/block, 16B/lane f32x4 loads. tgt = emb*keep ; srcb = bf16(emb*tl)
__global__ __launch_bounds__(256) void prep_kernel(const int* __restrict__ logs,
                                                   const float* __restrict__ emb,
                                                   float* __restrict__ tgt,
                                                   ushort_t* __restrict__ srcb) {
    int wid = threadIdx.x >> 6, lane = threadIdx.x & 63;
    int row = blockIdx.x * 4 + wid;          // BL % 4 == 0
    bool src = (logs[row] == 0);
    float kf = src ? 0.f : 1.f, sf = src ? 1.f : 0.f;
    size_t base = (size_t)row * DD;
    int c0 = lane * 4, c1 = c0 + 256;
    f32x4 e0 = *(const f32x4*)(emb + base + c0);
    f32x4 e1 = *(const f32x4*)(emb + base + c1);
    f32x4 t0, t1;
    short4v s0, s1;
    #pragma unroll
    for (int j = 0; j < 4; j++) {
        t0[j] = e0[j] * kf;
        t1[j] = e1[j] * kf;
        s0[j] = (short)f2b(e0[j] * sf);
        s1[j] = (short)f2b(e1[j] * sf);
    }
    *(f32x4*)(tgt + base + c0) = t0;
    *(f32x4*)(tgt + base + c1) = t1;
    *(short4v*)(srcb + base + c0) = s0;
    *(short4v*)(srcb + base + c1) = s1;
}

// fused weight transpose + bf16 for all 10 matrices: grid (16,16,10)
__global__ __launch_bounds__(256) void wtrans10_kernel(const float* __restrict__ Wq,
                                                       const float* __restrict__ Wk,
                                                       const float* __restrict__ Wv,
                                                       const float* __restrict__ W1,
                                                       const float* __restrict__ W2,
                                                       ushort_t* __restrict__ WqkvT,
                                                       ushort_t* __restrict__ W1T,
                                                       ushort_t* __restrict__ W2T) {
    __shared__ float ts[32][33];
    int tx = threadIdx.x & 31, ty = threadIdx.x >> 5;
    int bx = blockIdx.x * 32, by = blockIdx.y * 32;
    int z = blockIdx.z;
    const float* Wm;
    ushort_t* Wtm;
    if (z < 6) {
        int i = z / 3, j = z - 3 * i;
        const float* src = (j == 0) ? Wq : (j == 1) ? Wk : Wv;
        Wm = src + (size_t)i * DD * DD;
        Wtm = WqkvT + (size_t)z * DD * DD;
    } else if (z < 8) {
        Wm = W1 + (size_t)(z - 6) * DD * DD;
        Wtm = W1T + (size_t)(z - 6) * DD * DD;
    } else {
        Wm = W2 + (size_t)(z - 8) * DD * DD;
        Wtm = W2T + (size_t)(z - 8) * DD * DD;
    }
    #pragma unroll
    for (int i = 0; i < 4; i++) {
        int r = ty + i * 8;
        ts[r][tx] = Wm[(size_t)(by + r) * DD + bx + tx];
    }
    __syncthreads();
    #pragma unroll
    for (int i = 0; i < 4; i++) {
        int r = ty + i * 8;
        Wtm[(size_t)(bx + r) * DD + by + tx] = f2b(ts[tx][r]);
    }
}

// ------- layernorm v3: one wave per row, 4 rows/block, no LDS, no barrier ------
__global__ __launch_bounds__(256) void ln_kernel(const float* __restrict__ x,
                                                 const float* __restrict__ addx,
                                                 float* __restrict__ outf,
                                                 ushort_t* __restrict__ outb,
                                                 const float* __restrict__ g,
                                                 const float* __restrict__ bt,
                                                 const float* __restrict__ keepf) {
    int wid = threadIdx.x >> 6, lane = threadIdx.x & 63;
    int row = blockIdx.x * 4 + wid;          // BL % 4 == 0 -> always in range
    size_t base = (size_t)row * DD;
    int c0 = lane * 4, c1 = c0 + 256;
    f32x4 v0 = *(const f32x4*)(x + base + c0);
    f32x4 v1 = *(const f32x4*)(x + base + c1);
    if (addx) {
        f32x4 a0 = *(const f32x4*)(addx + base + c0);
        f32x4 a1 = *(const f32x4*)(addx + base + c1);
        v0 = v0 + a0;
        v1 = v1 + a1;
    }
    float s = v0[0] + v0[1] + v0[2] + v0[3] + v1[0] + v1[1] + v1[2] + v1[3];
    float sq = v0[0] * v0[0] + v0[1] * v0[1] + v0[2] * v0[2] + v0[3] * v0[3]
             + v1[0] * v1[0] + v1[1] * v1[1] + v1[2] * v1[2] + v1[3] * v1[3];
    #pragma unroll
    for (int off = 32; off; off >>= 1) {
        s += __shfl_xor(s, off);
        sq += __shfl_xor(sq, off);
    }
    float mean = s * (1.f / DD);
    float var = sq * (1.f / DD) - mean * mean;
    float rstd = rsqrtf(fmaxf(var, 0.f) + 1e-8f);
    float kf = keepf ? keepf[row] : 1.f;
    f32x4 g0 = *(const f32x4*)(g + c0), g1 = *(const f32x4*)(g + c1);
    f32x4 b0 = *(const f32x4*)(bt + c0), b1 = *(const f32x4*)(bt + c1);
    f32x4 o0, o1;
    #pragma unroll
    for (int j = 0; j < 4; j++) {
        o0[j] = ((v0[j] - mean) * rstd * g0[j] + b0[j]) * kf;
        o1[j] = ((v1[j] - mean) * rstd * g1[j] + b1[j]) * kf;
    }
    if (outf) {
        *(f32x4*)(outf + base + c0) = o0;
        *(f32x4*)(outf + base + c1) = o1;
    }
    if (outb) {
        short4v ob0, ob1;
        #pragma unroll
        for (int j = 0; j < 4; j++) { ob0[j] = (short)f2b(o0[j]); ob1[j] = (short)f2b(o1[j]); }
        *(short4v*)(outb + base + c0) = ob0;
        *(short4v*)(outb + base + c1) = ob1;
    }
}

// ------- bf16 MFMA GEMM, 64x128 tile, panel-major + XCD swizzle ----------------
// Round-13: REVERT of round-12's half-K-step pipeline (regression: VGPR 64->84,
// Occ 27->22, dur 42.5->48.4 — implicit multi-block overlap already hid the
// stage latency; the pipeline only cost registers. Guide Common-mistake #5
// confirmed empirically). K-loop = proven round-11 structure. Two additions:
// (a) kv blocks FIRST in the grid (bid<nkv) so their work overlaps the dense
//     ramp instead of extending the tail; (b) mode-2 issues Cf oldv loads
//     BEFORE the staging barrier (latency hides under LDS writes + barrier).
// mode 0: Cb = bf16(acc+bias) ; 1: Cb = bf16(relu) ; 2: Cf = (Cf+acc+bias)*keepf
__global__ __launch_bounds__(256) void gemm_mfma(const ushort_t* __restrict__ A,
                                                 const ushort_t* __restrict__ Bt,
                                                 const float* __restrict__ bias,
                                                 float* __restrict__ Cf,
                                                 ushort_t* __restrict__ Cb,
                                                 const float* __restrict__ keepf,
                                                 int mode, int M, int N, int K,
                                                 int ngg, int nkv,
                                                 const ushort_t* __restrict__ Akv,
                                                 const ushort_t* __restrict__ Bkv,
                                                 const float* __restrict__ bk,
                                                 const float* __restrict__ bv,
                                                 const int* __restrict__ rows,
                                                 const int* __restrict__ nbk,
                                                 ushort_t* __restrict__ kc,
                                                 ushort_t* __restrict__ vc) {
    __shared__ ushort_t smem[12288];       // 24 KB: K-loop sA(8K)+sB(16K); epilogue C-stage
    ushort_t* sAm = smem;                  // [2][64*32]
    ushort_t* sBm = smem + 4096;           // [2][128*32]
    int t = threadIdx.x;
    int w = t >> 6, lane = t & 63;
    int lr = lane & 15, lq = lane >> 4;
    int eA = t * 8, rowA = eA >> 5, colA = eA & 31;

    if ((int)blockIdx.x >= nkv) {
        // ---------------- main dense path ----------------
        int dbid = blockIdx.x - nkv;
        int cpx = ngg >> 3;
        int swz = (dbid & 7) * cpx + (dbid >> 3);
        int m0 = (swz >> 2) * 64;        // N/128 == 4 panels-per-row here (N=512)
        int n0 = (swz & 3) * 128;

        f32x4 acc[4][2] = {};

        for (int k0 = 0; k0 < K; k0 += 64) {
            #pragma unroll
            for (int hh = 0; hh < 2; hh++) {
                gload16(A + (size_t)(m0 + rowA) * K + k0 + hh * 32 + colA,
                        sAm + hh * 2048 + (w * 64) * 8);
                #pragma unroll
                for (int r = 0; r < 2; r++) {
                    int e = (r * 256 + t) * 8;
                    int row = e >> 5, col = e & 31;
                    gload16(Bt + (size_t)(n0 + row) * K + k0 + hh * 32 + col,
                            sBm + hh * 4096 + (r * 256 + w * 64) * 8);
                }
            }
            __syncthreads();

            #pragma unroll
            for (int hh = 0; hh < 2; hh++) {
                short8 af[4], bf[2];
                #pragma unroll
                for (int mt = 0; mt < 4; mt++)
                    af[mt] = *(const short8*)(sAm + hh * 2048 + (mt * 16 + lr) * 32 + lq * 8);
                #pragma unroll
                for (int nt = 0; nt < 2; nt++)
                    bf[nt] = *(const short8*)(sBm + hh * 4096 + (w * 32 + nt * 16 + lr) * 32 + lq * 8);
                #pragma unroll
                for (int mt = 0; mt < 4; mt++)
                    #pragma unroll
                    for (int nt = 0; nt < 2; nt++)
                        acc[mt][nt] = __builtin_amdgcn_mfma_f32_16x16x32_bf16(af[mt], bf[nt], acc[mt][nt], 0, 0, 0);
            }
            __syncthreads();
        }

        if (mode != 2) {
            #pragma unroll
            for (int nt = 0; nt < 2; nt++) {
                int colL = w * 32 + nt * 16 + lr;
                float bvv = bias[n0 + colL];
                #pragma unroll
                for (int mt = 0; mt < 4; mt++) {
                    int rowL = mt * 16 + lq * 4;
                    #pragma unroll
                    for (int r = 0; r < 4; r++) {
                        float o = acc[mt][nt][r] + bvv;
                        if (mode == 1) o = fmaxf(o, 0.f);
                        smem[(rowL + r) * 136 + colL] = f2b(o);
                    }
                }
            }
            __syncthreads();
            int rr = t >> 2, cc = (t & 3) * 32;
            #pragma unroll
            for (int j = 0; j < 4; j++) {
                short8 vv = *(const short8*)(smem + rr * 136 + cc + j * 8);
                *(short8*)(Cb + (size_t)(m0 + rr) * N + n0 + cc + j * 8) = vv;
            }
        } else {
            float* sf = (float*)smem;
            int rr = t >> 3, cc = (t & 7) * 16;
            #pragma unroll
            for (int half = 0; half < 2; half++) {
                // issue oldv loads EARLY — latency hides under staging + barrier
                int grow = m0 + half * 32 + rr;
                f32x4 oldv[4];
                #pragma unroll
                for (int j = 0; j < 4; j++)
                    oldv[j] = *(const f32x4*)(Cf + (size_t)grow * N + n0 + cc + j * 4);
                #pragma unroll
                for (int nt = 0; nt < 2; nt++) {
                    int colL = w * 32 + nt * 16 + lr;
                    float bvv = bias[n0 + colL];
                    #pragma unroll
                    for (int mt = half * 2; mt < half * 2 + 2; mt++) {
                        int rowL = mt * 16 + lq * 4 - half * 32;
                        #pragma unroll
                        for (int r = 0; r < 4; r++)
                            sf[(rowL + r) * 132 + colL] = acc[mt][nt][r] + bvv;
                    }
                }
                __syncthreads();
                float kf = keepf[grow];
                #pragma unroll
                for (int j = 0; j < 4; j++) {
                    f32x4 nv;
                    #pragma unroll
                    for (int x = 0; x < 4; x++)
                        nv[x] = (oldv[j][x] + sf[rr * 132 + cc + j * 4 + x]) * kf;
                    *(f32x4*)(Cf + (size_t)grow * N + n0 + cc + j * 4) = nv;
                }
                __syncthreads();
            }
        }
    } else {
        // ---------------- compact K/V path (mode 0, blocks 0..nkv-1) ------------
        // eb: z = eb>>5 (0=K,1=V), n-col = (eb>>3)&3, m-tile start = eb&7
        int eb = blockIdx.x;
        int z = eb >> 5;
        int n0 = ((eb >> 3) & 3) * 128;
        int mt0 = eb & 7;
        const ushort_t* Btk = Bkv + (size_t)z * DD * DD;
        const float* biask = z ? bv : bk;
        ushort_t* C = z ? vc : kc;
        int rowlim = nbk[0] * 128;           // rows[] valid/padded up to here

        for (int mt = mt0; mt * 64 < rowlim; mt += 8) {
            int m0c = mt * 64;
            int ra = rows[m0c + rowA];       // gathered source row (K-invariant)

            f32x4 acc[4][2] = {};

            for (int k0 = 0; k0 < DD; k0 += 64) {
                #pragma unroll
                for (int hh = 0; hh < 2; hh++) {
                    gload16(Akv + (size_t)ra * DD + k0 + hh * 32 + colA,
                            sAm + hh * 2048 + (w * 64) * 8);
                    #pragma unroll
                    for (int r = 0; r < 2; r++) {
                        int e = (r * 256 + t) * 8;
                        int row = e >> 5, col = e & 31;
                        gload16(Btk + (size_t)(n0 + row) * DD + k0 + hh * 32 + col,
                                sBm + hh * 4096 + (r * 256 + w * 64) * 8);
                    }
                }
                __syncthreads();

                #pragma unroll
                for (int hh = 0; hh < 2; hh++) {
                    short8 af[4], bf[2];
                    #pragma unroll
                    for (int mt2 = 0; mt2 < 4; mt2++)
                        af[mt2] = *(const short8*)(sAm + hh * 2048 + (mt2 * 16 + lr) * 32 + lq * 8);
                    #pragma unroll
                    for (int nt = 0; nt < 2; nt++)
                        bf[nt] = *(const short8*)(sBm + hh * 4096 + (w * 32 + nt * 16 + lr) * 32 + lq * 8);
                    #pragma unroll
                    for (int mt2 = 0; mt2 < 4; mt2++)
                        #pragma unroll
                        for (int nt = 0; nt < 2; nt++)
                            acc[mt2][nt] = __builtin_amdgcn_mfma_f32_16x16x32_bf16(af[mt2], bf[nt], acc[mt2][nt], 0, 0, 0);
                }
                __syncthreads();
            }

            #pragma unroll
            for (int nt = 0; nt < 2; nt++) {
                int colL = w * 32 + nt * 16 + lr;
                float bvv = biask[n0 + colL];
                #pragma unroll
                for (int mt2 = 0; mt2 < 4; mt2++) {
                    int rowL = mt2 * 16 + lq * 4;
                    #pragma unroll
                    for (int r = 0; r < 4; r++)
                        smem[(rowL + r) * 136 + colL] = f2b(acc[mt2][nt][r] + bvv);
                }
            }
            __syncthreads();
            int rr = t >> 2, cc = (t & 3) * 32;
            #pragma unroll
            for (int j = 0; j < 4; j++) {
                short8 vv = *(const short8*)(smem + rr * 136 + cc + j * 8);
                *(short8*)(C + (size_t)(m0c + rr) * DD + n0 + cc + j * 8) = vv;
            }
            __syncthreads();   // smem reused by next m-tile's staging
        }
    }
}

// ---------------- sparse attention v4: 8 lanes/query, LDS keys, e=0 masking ----
__global__ __launch_bounds__(256) void attn_sparse(const ushort_t* __restrict__ q,
                                                   const ushort_t* __restrict__ kc,
                                                   const ushort_t* __restrict__ vc,
                                                   const int* __restrict__ kidx,
                                                   const int* __restrict__ cntb,
                                                   const int* __restrict__ off,
                                                   float* __restrict__ xout) {
    __shared__ ushort_t sK[SCAP * DK];   // 8 KB
    __shared__ ushort_t sV[SCAP * DK];   // 8 KB
    __shared__ int sIdx[LL];             // 800 B
    int b = blockIdx.x >> 3, h = blockIdx.x & 7;
    int t = threadIdx.x;
    int w = t >> 6, lane = t & 63;
    int qi = lane >> 3;                  // query slot 0..7 within wave
    int dc = (lane & 7) * 8;             // head-dim chunk base (8 dims/lane)
    int nc = cntb[b], ob = off[b];
    const ushort_t* qg = q + (size_t)b * LL * DD + h * DK;
    float* og = xout + (size_t)b * LL * DD + h * DK;
    const ushort_t* kb2 = kc + (size_t)ob * DD + h * DK;
    const ushort_t* vb2 = vc + (size_t)ob * DD + h * DK;

    if (t < nc) sIdx[t] = kidx[b * LL + t];          // nc <= 200 < 256
    int ns = (nc < SCAP) ? nc : SCAP;
    for (int idx = t; idx < ns * 8; idx += 256) {    // 8x 16B chunks per 128B row
        int s = idx >> 3, c = (idx & 7) * 8;
        *(uint4*)(sK + s * DK + c) = *(const uint4*)(kb2 + (size_t)s * DD + c);
        *(uint4*)(sV + s * DK + c) = *(const uint4*)(vb2 + (size_t)s * DD + c);
    }
    __syncthreads();

    // 32 queries per block-iteration (4 waves x 8); 7 iterations cover 224 >= LL
    for (int i0 = 0; i0 < LL; i0 += 32) {
        int i = i0 + w * 8 + qi;
        bool qok = (i < LL);
        int ic = qok ? i : (LL - 1);
        short8 qv = *(const short8*)(qg + (size_t)ic * DD + dc);
        float qf[8];
        #pragma unroll
        for (int j = 0; j < 8; j++) qf[j] = b2f((ushort_t)qv[j]);

        float m = -3.0e38f, l = 0.f;
        float acc[8];
        #pragma unroll
        for (int j = 0; j < 8; j++) acc[j] = 0.f;

        for (int s = 0; s < nc; s++) {
            const ushort_t* kp = (s < SCAP) ? (sK + s * DK + dc)
                                            : (kb2 + (size_t)s * DD + dc);
            const ushort_t* vp = (s < SCAP) ? (sV + s * DK + dc)
                                            : (vb2 + (size_t)s * DD + dc);
            short8 k8 = *(const short8*)kp;
            float pp = 0.f;
            #pragma unroll
            for (int j = 0; j < 8; j++) pp += qf[j] * b2f((ushort_t)k8[j]);
            pp += __shfl_xor(pp, 1);
            pp += __shfl_xor(pp, 2);
            pp += __shfl_xor(pp, 4);
            bool ok = (sIdx[s] <= i);                // per-query causal predicate
            float sc = ok ? pp * 0.125f : -3.0e38f;
            float mn = fmaxf(m, sc);
            float e = ok ? __expf(sc - mn) : 0.f;    // masked key contributes 0
            float rs2 = __expf(m - mn);              // m==mn for masked -> rs2=1
            l = l * rs2 + e;
            short8 v8 = *(const short8*)vp;
            #pragma unroll
            for (int j = 0; j < 8; j++)
                acc[j] = acc[j] * rs2 + e * b2f((ushort_t)v8[j]);
            m = mn;
        }

        if (qok) {
            float inv = (l > 0.f) ? 1.f / l : 0.f;
            f32x4 o0, o1;
            #pragma unroll
            for (int j = 0; j < 4; j++) { o0[j] = acc[j] * inv; o1[j] = acc[j + 4] * inv; }
            *(f32x4*)(og + (size_t)i * DD + dc) = o0;
            *(f32x4*)(og + (size_t)i * DD + dc + 4) = o1;
        }
    }
}

extern "C" void kernel_launch(void* const* d_in, const int* in_sizes, int n_in,
                              void* d_out, int out_size, void* d_ws, size_t ws_size,
                              hipStream_t stream) {
    const int* log_seqs = (const int*)d_in[0];
    const float* seqs_embs = (const float*)d_in[1];
    const int* entire = (const int*)d_in[2];
    const float* Wq = (const float*)d_in[3];
    const float* bq = (const float*)d_in[4];
    const float* Wk = (const float*)d_in[5];
    const float* bk = (const float*)d_in[6];
    const float* Wv = (const float*)d_in[7];
    const float* bv = (const float*)d_in[8];
    const float* lag = (const float*)d_in[9];
    const float* lab = (const float*)d_in[10];
    const float* lfg = (const float*)d_in[11];
    const float* lfb = (const float*)d_in[12];
    const float* W1 = (const float*)d_in[13];
    const float* b1 = (const float*)d_in[14];
    const float* W2 = (const float*)d_in[15];
    const float* b2 = (const float*)d_in[16];
    const float* llg = (const float*)d_in[17];
    const float* llb = (const float*)d_in[18];
    float* out = (float*)d_out;
    float* ws = (float*)d_ws;

    // workspace ~241 MB (262.45 MB proven safe)
    const size_t n = (size_t)BL * DD;
    float* tgt = ws;
    float* aout = ws + n;
    ushort_t* srcb = (ushort_t*)(ws + 2 * n);
    ushort_t* qb = srcb + n;
    ushort_t* kc = qb + n;           // compact K rows [<=BL][DD]
    ushort_t* lnb = kc + n;
    ushort_t* WqkvT = lnb + n;
    ushort_t* W1T = WqkvT + (size_t)NBLK * 3 * DD * DD;
    ushort_t* W2T = W1T + (size_t)NBLK * DD * DD;
    float* keepf = (float*)(W2T + (size_t)NBLK * DD * DD);
    float* kmf = keepf + BL;
    ushort_t* vc = (ushort_t*)(kmf + BL);   // compact V rows [<=BL][DD]
    int* kidx = (int*)(vc + n);      // [BB][LL] per-batch valid key indices
    int* cntb = kidx + BL;           // [BB]
    int* offb = cntb + BB;           // [BB]
    int* rows = offb + BB;           // [BL+128] global gathered row list (padded)
    int* nbk = rows + BL + 128;      // [1] number of 128-row tiles
    ushort_t* hb = qb;               // FFN1 out: qb dead after attention

    maskidx_kernel<<<BB, 256, 0, stream>>>(log_seqs, entire, keepf, kmf, kidx, cntb);
    scan_kernel<<<1, 128, 0, stream>>>(cntb, kidx, offb, rows, nbk);
    prep_kernel<<<BL / 4, 256, 0, stream>>>(log_seqs, seqs_embs, tgt, srcb);
    dim3 tw(16, 16, 10);
    wtrans10_kernel<<<tw, 256, 0, stream>>>(Wq, Wk, Wv, W1, W2, WqkvT, W1T, W2T);

    int ngg = (BL / 64) * (DD / 128);   // 1600 dense blocks, panel-major + XCD swizzle
    int nln = BL / 4;                   // LN: 4 rows per 256-thread block
    for (int i = 0; i < NBLK; i++) {
        size_t wo = (size_t)i * DD * DD;
        const ushort_t* Wi = WqkvT + (size_t)i * 3 * DD * DD;
        // lnb = bf16(LN(tgt, ln_attn))
        ln_kernel<<<nln, 256, 0, stream>>>(tgt, nullptr, nullptr, lnb,
                                           lag + i * DD, lab + i * DD, nullptr);
        // merged: compact kc/vc projections (64 blocks FIRST) + qb = bf16(lnb@Wq+bq)
        gemm_mfma<<<ngg + 64, 256, 0, stream>>>(lnb, Wi, bq + i * DD, nullptr, qb,
                                                nullptr, 0, BL, DD, DD, ngg, 64,
                                                srcb, Wi + (size_t)DD * DD,
                                                bk + i * DD, bv + i * DD,
                                                rows, nbk, kc, vc);
        // attention over compacted keys -> aout fp32
        attn_sparse<<<BB * HH, 256, 0, stream>>>(qb, kc, vc, kidx, cntb, offb, aout);
        // tgt = LN(aout (+tgt)), bf16 copy to lnb
        ln_kernel<<<nln, 256, 0, stream>>>(aout, (i == 0) ? nullptr : tgt, tgt, lnb,
                                           lfg + i * DD, lfb + i * DD, nullptr);
        // hb = bf16(relu(lnb @ W1 + b1))
        gemm_mfma<<<ngg, 256, 0, stream>>>(lnb, W1T + wo, b1 + i * DD, nullptr, hb,
                                           nullptr, 1, BL, DD, DD, ngg, 0,
                                           nullptr, nullptr, nullptr, nullptr,
                                           nullptr, nullptr, nullptr, nullptr);
        // tgt = (tgt + hb @ W2 + b2) * keep
        gemm_mfma<<<ngg, 256, 0, stream>>>(hb, W2T + wo, b2 + i * DD, tgt, nullptr,
                                           keepf, 2, BL, DD, DD, ngg, 0,
                                           nullptr, nullptr, nullptr, nullptr,
                                           nullptr, nullptr, nullptr, nullptr);
    }
    ln_kernel<<<nln, 256, 0, stream>>>(tgt, nullptr, out, nullptr, llg, llb, keepf);
}